// Round 1
// baseline (140.693 us; speedup 1.0000x reference)
//
#include <hip/hip_runtime.h>

// Problem constants (from reference setup_inputs).
#define BATCH  4
#define NQ     8192
#define NA     6890
#define NSPLIT 8     // anchor splits = waves per block
#define QPB    64    // queries per block = one wave width

__global__ __launch_bounds__(512)
void collision_kernel(const float* __restrict__ query,
                      const float* __restrict__ anchor,
                      const float* __restrict__ normals,
                      float* __restrict__ out) {
    __shared__ float s_d2[NSPLIT][QPB];
    __shared__ int   s_ix[NSPLIT][QPB];

    const int lane = threadIdx.x & 63;
    // Force wave index into an SGPR so anchor loads are provably wave-uniform.
    const int wave = __builtin_amdgcn_readfirstlane((int)(threadIdx.x >> 6));
    const int blocksPerBatch = NQ / QPB;                  // 128
    const int b = blockIdx.x / blocksPerBatch;
    const int q = (blockIdx.x % blocksPerBatch) * QPB + lane;

    const float* qp = query + ((size_t)b * NQ + q) * 3;
    const float qx = qp[0], qy = qp[1], qz = qp[2];

    const float* __restrict__ A = anchor + (size_t)b * NA * 3;

    // Contiguous anchor range for this wave (uniform bounds).
    const int per = (NA + NSPLIT - 1) / NSPLIT;           // 862
    const int k0 = wave * per;
    const int k1 = (k0 + per < NA) ? (k0 + per) : NA;

    // Two independent min/argmin chains (even/odd) for ILP.
    float bd0 = 1e30f, bd1 = 1e30f;
    int   bi0 = 0,     bi1 = 0;
    int k = k0;
    for (; k + 1 < k1; k += 2) {
        const float ax0 = A[3*k+0], ay0 = A[3*k+1], az0 = A[3*k+2];
        const float ax1 = A[3*k+3], ay1 = A[3*k+4], az1 = A[3*k+5];
        const float dx0 = qx-ax0, dy0 = qy-ay0, dz0 = qz-az0;
        const float dx1 = qx-ax1, dy1 = qy-ay1, dz1 = qz-az1;
        const float d20 = dx0*dx0 + dy0*dy0 + dz0*dz0;
        const float d21 = dx1*dx1 + dy1*dy1 + dz1*dz1;
        if (d20 < bd0) { bd0 = d20; bi0 = k; }
        if (d21 < bd1) { bd1 = d21; bi1 = k + 1; }
    }
    if (k < k1) {
        const float ax = A[3*k+0], ay = A[3*k+1], az = A[3*k+2];
        const float dx = qx-ax, dy = qy-ay, dz = qz-az;
        const float d2 = dx*dx + dy*dy + dz*dz;
        if (d2 < bd0) { bd0 = d2; bi0 = k; }
    }
    // Merge chains; lexicographic (d2, idx) so lowest index wins ties
    // (matches jnp.argmin first-occurrence semantics).
    float bd = bd0; int bi = bi0;
    if (bd1 < bd || (bd1 == bd && bi1 < bi)) { bd = bd1; bi = bi1; }

    s_d2[wave][lane] = bd;
    s_ix[wave][lane] = bi;
    __syncthreads();

    if (threadIdx.x < QPB) {
        float best = s_d2[0][lane];
        int   bidx = s_ix[0][lane];
        #pragma unroll
        for (int s = 1; s < NSPLIT; ++s) {
            const float d = s_d2[s][lane];
            const int   i = s_ix[s][lane];
            if (d < best || (d == best && i < bidx)) { best = d; bidx = i; }
        }
        // Gather NN anchor + normal, compute collision predicate.
        const float* ap = A + (size_t)bidx * 3;
        const float* np = normals + ((size_t)b * NA + bidx) * 3;
        const float dx = qx - ap[0], dy = qy - ap[1], dz = qz - ap[2];
        const float dot = dx*np[0] + dy*np[1] + dz*np[2];
        // dot * (l2 <= 0.5) < 0  <=>  dot < 0 && d2 <= 0.25
        const bool coll = (dot < 0.0f) && (best <= 0.25f);
        const unsigned long long m = __ballot(coll);
        if (lane == 0) atomicAdd(out + b, (float)__popcll(m));
    }
}

extern "C" void kernel_launch(void* const* d_in, const int* in_sizes, int n_in,
                              void* d_out, int out_size, void* d_ws, size_t ws_size,
                              hipStream_t stream) {
    const float* query   = (const float*)d_in[0];
    const float* anchor  = (const float*)d_in[1];
    const float* normals = (const float*)d_in[2];
    float* out = (float*)d_out;

    // d_out is poisoned with 0xAA before every call — zero it (graph-safe).
    hipMemsetAsync(d_out, 0, (size_t)out_size * sizeof(float), stream);

    const int grid = BATCH * (NQ / QPB);   // 512 blocks
    collision_kernel<<<dim3(grid), dim3(512), 0, stream>>>(query, anchor, normals, out);
}

// Round 2
// 129.931 us; speedup vs baseline: 1.0828x; 1.0828x over previous
//
#include <hip/hip_runtime.h>

// Problem constants (from reference setup_inputs).
#define BATCH  4
#define NQ     8192
#define NA     6890
#define NSPLIT 16    // anchor splits = waves per block
#define QPB    64    // queries per block-column = one wave width
#define PER    432   // ceil(NA/NSPLIT) rounded up to mult of 4 -> 16B-aligned chunk starts

__global__ __launch_bounds__(NSPLIT * 64)
void collision_kernel(const float* __restrict__ query,
                      const float* __restrict__ anchor,
                      const float* __restrict__ normals,
                      float* __restrict__ out) {
    __shared__ float s_d2[NSPLIT][QPB];
    __shared__ int   s_ix[NSPLIT][QPB];

    const int lane = threadIdx.x & 63;
    // Force wave index into an SGPR so anchor loads are provably wave-uniform.
    const int wave = __builtin_amdgcn_readfirstlane((int)(threadIdx.x >> 6));
    const int blocksPerBatch = NQ / QPB;                  // 128
    const int b = blockIdx.x / blocksPerBatch;
    const int q = (blockIdx.x % blocksPerBatch) * QPB + lane;

    const float* qp = query + ((size_t)b * NQ + q) * 3;
    const float qx = qp[0], qy = qp[1], qz = qp[2];

    const float* __restrict__ A = anchor + (size_t)b * NA * 3;

    // Contiguous anchor range for this wave (uniform bounds, 4-anchor aligned start).
    const int k0 = wave * PER;
    const int k1 = (k0 + PER < NA) ? (k0 + PER) : NA;
    const int n  = k1 - k0;                               // 432 except last wave: 410
    const float* __restrict__ P = A + (size_t)3 * k0;

    // 4 independent min/argmin chains for ILP.
    float bd0 = 1e30f, bd1 = 1e30f, bd2 = 1e30f, bd3 = 1e30f;
    int   bi0 = k0,    bi1 = k0,    bi2 = k0,    bi3 = k0;

    int k = 0;
    if (n >= 4) {
        // Software-pipelined: prefetch next 4 anchors (12 uniform floats ->
        // 3x s_load_dwordx4) while computing the current 4.
        float c0,c1,c2,c3,c4,c5,c6,c7,c8,c9,c10,c11;
        {
            const float* s = P;
            c0=s[0]; c1=s[1]; c2=s[2]; c3=s[3]; c4=s[4]; c5=s[5];
            c6=s[6]; c7=s[7]; c8=s[8]; c9=s[9]; c10=s[10]; c11=s[11];
        }
        for (k = 0; k + 8 <= n; k += 4) {
            const float* s = P + 3 * (k + 4);
            const float t0=s[0], t1=s[1], t2=s[2], t3=s[3], t4=s[4], t5=s[5],
                        t6=s[6], t7=s[7], t8=s[8], t9=s[9], t10=s[10], t11=s[11];
            {
                const float dx0=qx-c0,  dy0=qy-c1,  dz0=qz-c2;
                const float dx1=qx-c3,  dy1=qy-c4,  dz1=qz-c5;
                const float dx2=qx-c6,  dy2=qy-c7,  dz2=qz-c8;
                const float dx3=qx-c9,  dy3=qy-c10, dz3=qz-c11;
                const float d0=dx0*dx0+dy0*dy0+dz0*dz0;
                const float d1=dx1*dx1+dy1*dy1+dz1*dz1;
                const float d2=dx2*dx2+dy2*dy2+dz2*dz2;
                const float d3=dx3*dx3+dy3*dy3+dz3*dz3;
                const int kk = k0 + k;
                if (d0 < bd0) { bd0 = d0; bi0 = kk;     }
                if (d1 < bd1) { bd1 = d1; bi1 = kk + 1; }
                if (d2 < bd2) { bd2 = d2; bi2 = kk + 2; }
                if (d3 < bd3) { bd3 = d3; bi3 = kk + 3; }
            }
            c0=t0; c1=t1; c2=t2; c3=t3; c4=t4; c5=t5;
            c6=t6; c7=t7; c8=t8; c9=t9; c10=t10; c11=t11;
        }
        {   // epilogue chunk (no prefetch)
            const float dx0=qx-c0,  dy0=qy-c1,  dz0=qz-c2;
            const float dx1=qx-c3,  dy1=qy-c4,  dz1=qz-c5;
            const float dx2=qx-c6,  dy2=qy-c7,  dz2=qz-c8;
            const float dx3=qx-c9,  dy3=qy-c10, dz3=qz-c11;
            const float d0=dx0*dx0+dy0*dy0+dz0*dz0;
            const float d1=dx1*dx1+dy1*dy1+dz1*dz1;
            const float d2=dx2*dx2+dy2*dy2+dz2*dz2;
            const float d3=dx3*dx3+dy3*dy3+dz3*dz3;
            const int kk = k0 + k;
            if (d0 < bd0) { bd0 = d0; bi0 = kk;     }
            if (d1 < bd1) { bd1 = d1; bi1 = kk + 1; }
            if (d2 < bd2) { bd2 = d2; bi2 = kk + 2; }
            if (d3 < bd3) { bd3 = d3; bi3 = kk + 3; }
            k += 4;
        }
    }
    for (; k < n; ++k) {   // scalar tail (last wave: 410 = 4*102 + 2)
        const float ax = P[3*k+0], ay = P[3*k+1], az = P[3*k+2];
        const float dx = qx-ax, dy = qy-ay, dz = qz-az;
        const float d2 = dx*dx + dy*dy + dz*dz;
        if (d2 < bd0) { bd0 = d2; bi0 = k0 + k; }
    }

    // Merge chains; lexicographic (d2, idx) preserves first-occurrence ties.
    float bd = bd0; int bi = bi0;
    if (bd1 < bd || (bd1 == bd && bi1 < bi)) { bd = bd1; bi = bi1; }
    if (bd2 < bd || (bd2 == bd && bi2 < bi)) { bd = bd2; bi = bi2; }
    if (bd3 < bd || (bd3 == bd && bi3 < bi)) { bd = bd3; bi = bi3; }

    s_d2[wave][lane] = bd;
    s_ix[wave][lane] = bi;
    __syncthreads();

    if (threadIdx.x < QPB) {
        float best = s_d2[0][lane];
        int   bidx = s_ix[0][lane];
        #pragma unroll
        for (int s = 1; s < NSPLIT; ++s) {
            const float d = s_d2[s][lane];
            const int   i = s_ix[s][lane];
            if (d < best || (d == best && i < bidx)) { best = d; bidx = i; }
        }
        // Gather NN anchor + normal, compute collision predicate.
        const float* ap = A + (size_t)bidx * 3;
        const float* np = normals + ((size_t)b * NA + bidx) * 3;
        const float dx = qx - ap[0], dy = qy - ap[1], dz = qz - ap[2];
        const float dot = dx*np[0] + dy*np[1] + dz*np[2];
        // dot * (l2 <= 0.5) < 0  <=>  dot < 0 && d2 <= 0.25
        const bool coll = (dot < 0.0f) && (best <= 0.25f);
        const unsigned long long m = __ballot(coll);
        if (lane == 0) atomicAdd(out + b, (float)__popcll(m));
    }
}

extern "C" void kernel_launch(void* const* d_in, const int* in_sizes, int n_in,
                              void* d_out, int out_size, void* d_ws, size_t ws_size,
                              hipStream_t stream) {
    const float* query   = (const float*)d_in[0];
    const float* anchor  = (const float*)d_in[1];
    const float* normals = (const float*)d_in[2];
    float* out = (float*)d_out;

    // d_out is poisoned with 0xAA before every call — zero it (graph-safe).
    hipMemsetAsync(d_out, 0, (size_t)out_size * sizeof(float), stream);

    const int grid = BATCH * (NQ / QPB);   // 512 blocks x 1024 threads
    collision_kernel<<<dim3(grid), dim3(NSPLIT * 64), 0, stream>>>(query, anchor, normals, out);
}

// Round 3
// 97.933 us; speedup vs baseline: 1.4366x; 1.3267x over previous
//
#include <hip/hip_runtime.h>

// Problem constants (from reference setup_inputs).
#define BATCH  4
#define NQ     8192
#define NA     6890
#define NSPLIT 16    // anchor splits = waves per block
#define QPB    64    // queries per block = one wave width
#define PER    432   // ceil(NA/NSPLIT) rounded to mult of 8

// 24 floats = 8 anchors per group, kept in SGPRs (wave-uniform loads).
#define DECL_BUF(p) \
  float p##00,p##01,p##02,p##03,p##04,p##05,p##06,p##07, \
        p##08,p##09,p##10,p##11,p##12,p##13,p##14,p##15, \
        p##16,p##17,p##18,p##19,p##20,p##21,p##22,p##23;

#define LOAD_BUF(p, sp) do { const float* _s = (sp); \
  p##00=_s[0];  p##01=_s[1];  p##02=_s[2];  p##03=_s[3]; \
  p##04=_s[4];  p##05=_s[5];  p##06=_s[6];  p##07=_s[7]; \
  p##08=_s[8];  p##09=_s[9];  p##10=_s[10]; p##11=_s[11]; \
  p##12=_s[12]; p##13=_s[13]; p##14=_s[14]; p##15=_s[15]; \
  p##16=_s[16]; p##17=_s[17]; p##18=_s[18]; p##19=_s[19]; \
  p##20=_s[20]; p##21=_s[21]; p##22=_s[22]; p##23=_s[23]; } while(0)

// Packed (d2,idx) key: d2>=0 so float bits order as uint; low 13 bits carry idx.
// v_min_u32 then gives argmin with first-occurrence tie-break.
#define EVAL1(ax,ay,az,idx,acc) do { \
  const float _dx = qx-(ax), _dy = qy-(ay), _dz = qz-(az); \
  const float _d  = fmaf(_dz,_dz, fmaf(_dy,_dy, _dx*_dx)); \
  const unsigned _key = (__float_as_uint(_d) & 0xFFFFE000u) | (unsigned)(idx); \
  acc = (_key < acc) ? _key : acc; } while(0)

#define COMP_BUF(p, kk) do { \
  EVAL1(p##00,p##01,p##02,(kk)+0,best0); \
  EVAL1(p##03,p##04,p##05,(kk)+1,best1); \
  EVAL1(p##06,p##07,p##08,(kk)+2,best0); \
  EVAL1(p##09,p##10,p##11,(kk)+3,best1); \
  EVAL1(p##12,p##13,p##14,(kk)+4,best0); \
  EVAL1(p##15,p##16,p##17,(kk)+5,best1); \
  EVAL1(p##18,p##19,p##20,(kk)+6,best0); \
  EVAL1(p##21,p##22,p##23,(kk)+7,best1); } while(0)

__global__ __launch_bounds__(NSPLIT * 64)
void collision_kernel(const float* __restrict__ query,
                      const float* __restrict__ anchor,
                      const float* __restrict__ normals,
                      float* __restrict__ out) {
    __shared__ unsigned s_key[NSPLIT][QPB];

    const int lane = threadIdx.x & 63;
    // Force wave index into an SGPR so anchor loads are provably wave-uniform.
    const int wave = __builtin_amdgcn_readfirstlane((int)(threadIdx.x >> 6));
    const int blocksPerBatch = NQ / QPB;                  // 128
    const int b = blockIdx.x / blocksPerBatch;
    const int q = (blockIdx.x % blocksPerBatch) * QPB + lane;

    const float* qp = query + ((size_t)b * NQ + q) * 3;
    const float qx = qp[0], qy = qp[1], qz = qp[2];

    const float* __restrict__ A = anchor + (size_t)b * NA * 3;

    // Contiguous anchor range for this wave (uniform bounds, 8-aligned start).
    const int k0 = wave * PER;
    const int k1 = (k0 + PER < NA) ? (k0 + PER) : NA;
    const int n  = k1 - k0;                               // 432; last wave 410
    const float* __restrict__ P = A + (size_t)3 * k0;

    unsigned best0 = 0xFFFFFFFFu, best1 = 0xFFFFFFFFu;

    const int ng = n >> 3;          // full 8-anchor groups
    DECL_BUF(c) DECL_BUF(t)
    if (ng >= 2) {
        LOAD_BUF(c, P);
        int g = 0;
        // True double-buffer: no register copies, 2 groups per trip.
        while (g + 2 < ng) {
            LOAD_BUF(t, P + 24 * (g + 1));
            COMP_BUF(c, k0 + 8 * g);
            LOAD_BUF(c, P + 24 * (g + 2));
            COMP_BUF(t, k0 + 8 * (g + 1));
            g += 2;
        }
        if (g + 1 < ng) {           // two groups remain
            LOAD_BUF(t, P + 24 * (g + 1));
            COMP_BUF(c, k0 + 8 * g);
            COMP_BUF(t, k0 + 8 * (g + 1));
        } else {                    // one group remains
            COMP_BUF(c, k0 + 8 * g);
        }
    } else if (ng == 1) {
        LOAD_BUF(c, P);
        COMP_BUF(c, k0);
    }
    for (int k = ng << 3; k < n; ++k) {   // scalar tail (last wave: 2)
        EVAL1(P[3*k+0], P[3*k+1], P[3*k+2], k0 + k, best0);
    }

    s_key[wave][lane] = (best1 < best0) ? best1 : best0;
    __syncthreads();

    if (threadIdx.x < QPB) {
        unsigned bk = s_key[0][lane];
        #pragma unroll
        for (int s = 1; s < NSPLIT; ++s) {
            const unsigned v = s_key[s][lane];
            bk = (v < bk) ? v : bk;
        }
        const int bidx = (int)(bk & 8191u);
        // Recompute exact d2 / dot for the selected NN.
        const float* ap = A + (size_t)bidx * 3;
        const float* np = normals + ((size_t)b * NA + bidx) * 3;
        const float dx = qx - ap[0], dy = qy - ap[1], dz = qz - ap[2];
        const float d2  = fmaf(dz, dz, fmaf(dy, dy, dx * dx));
        const float dot = fmaf(dz, np[2], fmaf(dy, np[1], dx * np[0]));
        // dot * (l2 <= 0.5) < 0  <=>  dot < 0 && d2 <= 0.25
        const bool coll = (dot < 0.0f) && (d2 <= 0.25f);
        const unsigned long long m = __ballot(coll);
        if (lane == 0) atomicAdd(out + b, (float)__popcll(m));
    }
}

extern "C" void kernel_launch(void* const* d_in, const int* in_sizes, int n_in,
                              void* d_out, int out_size, void* d_ws, size_t ws_size,
                              hipStream_t stream) {
    const float* query   = (const float*)d_in[0];
    const float* anchor  = (const float*)d_in[1];
    const float* normals = (const float*)d_in[2];
    float* out = (float*)d_out;

    // d_out is poisoned with 0xAA before every call — zero it (graph-safe).
    hipMemsetAsync(d_out, 0, (size_t)out_size * sizeof(float), stream);

    const int grid = BATCH * (NQ / QPB);   // 512 blocks x 1024 threads
    collision_kernel<<<dim3(grid), dim3(NSPLIT * 64), 0, stream>>>(query, anchor, normals, out);
}